// Round 8
// baseline (430.329 us; speedup 1.0000x reference)
//
#include <hip/hip_runtime.h>

#define NN 100000
#define NE 3200000
#define ET (NE + NN)
#define NEG_SLOPE 0.2f
#define BSH 7
#define WIN (1 << BSH)                     // 128 nodes per bucket
#define NBUC ((NN + WIN - 1) >> BSH)       // 782 buckets
#define NBLK 256                           // scatter blocks (one per CU)
#define EPB ((ET + NBLK - 1) / NBLK)       // edges per scatter block

// XCD-swizzled region column: blocks b and b+8 (same XCD under round-robin
// dispatch) get adjacent columns -> each 128B cnt/tmpp line is produced by one
// XCD, written back once (round-5/6: 6.4x/15x write amplification otherwise).
__device__ __host__ __forceinline__ int swz(int b) {
    return (b & 7) * (NBLK / 8) + (b >> 3);
}

__device__ __forceinline__ float lrelu(float v) { return v > 0.f ? v : NEG_SLOPE * v; }

// bf16 <-> f32
__device__ __forceinline__ unsigned short f2bf(float x) {
    unsigned u = __float_as_uint(x);
    return (unsigned short)((u + 0x7fffu + ((u >> 16) & 1u)) >> 16);
}
__device__ __forceinline__ float bflo(unsigned u) { return __uint_as_float(u << 16); }
__device__ __forceinline__ float bfhi(unsigned u) { return __uint_as_float(u & 0xffff0000u); }

// ---------------- GEMM+attn body (shared by fused and standalone kernels) ----------------

template <int FIN, int FOUT, int C>
__device__ __forceinline__ void gemm_attn_body(
    int idx, const float* __restrict__ x, const float* Ws,
    const float* __restrict__ a_src, const float* __restrict__ a_dst,
    unsigned short* __restrict__ h, float* __restrict__ esrc,
    float* __restrict__ edst, int N) {
    constexpr int HH = FOUT / C;
    constexpr int F4 = FOUT / 4;
    constexpr int TPH = C / 4;           // threads per head
    if (idx >= N * F4) return;
    int n = idx / F4, f4 = idx - n * F4;
    int fb = 4 * f4;
    const float4* xr = (const float4*)(x + (long)n * FIN);
    float a0 = 0.f, a1 = 0.f, a2 = 0.f, a3 = 0.f;
#pragma unroll
    for (int k4 = 0; k4 < FIN / 4; ++k4) {
        float4 xv = xr[k4];
        const float* wr = &Ws[(4 * k4) * FOUT + fb];
        float4 w0 = *(const float4*)(wr);
        float4 w1 = *(const float4*)(wr + FOUT);
        float4 w2 = *(const float4*)(wr + 2 * FOUT);
        float4 w3 = *(const float4*)(wr + 3 * FOUT);
        a0 = fmaf(xv.x, w0.x, a0); a1 = fmaf(xv.x, w0.y, a1);
        a2 = fmaf(xv.x, w0.z, a2); a3 = fmaf(xv.x, w0.w, a3);
        a0 = fmaf(xv.y, w1.x, a0); a1 = fmaf(xv.y, w1.y, a1);
        a2 = fmaf(xv.y, w1.z, a2); a3 = fmaf(xv.y, w1.w, a3);
        a0 = fmaf(xv.z, w2.x, a0); a1 = fmaf(xv.z, w2.y, a1);
        a2 = fmaf(xv.z, w2.z, a2); a3 = fmaf(xv.z, w2.w, a3);
        a0 = fmaf(xv.w, w3.x, a0); a1 = fmaf(xv.w, w3.y, a1);
        a2 = fmaf(xv.w, w3.z, a2); a3 = fmaf(xv.w, w3.w, a3);
    }
    unsigned short b0 = f2bf(a0), b1 = f2bf(a1), b2 = f2bf(a2), b3 = f2bf(a3);
    *(ushort4*)(h + (long)n * FOUT + fb) = make_ushort4(b0, b1, b2, b3);
    float q0 = bflo((unsigned)b0), q1 = bflo((unsigned)b1);
    float q2 = bflo((unsigned)b2), q3 = bflo((unsigned)b3);
    float vs = q0 * a_src[fb] + q1 * a_src[fb + 1] + q2 * a_src[fb + 2] + q3 * a_src[fb + 3];
    float vd = q0 * a_dst[fb] + q1 * a_dst[fb + 1] + q2 * a_dst[fb + 2] + q3 * a_dst[fb + 3];
#pragma unroll
    for (int o = 1; o < TPH; o <<= 1) {
        vs += __shfl_xor(vs, o);
        vd += __shfl_xor(vd, o);
    }
    if ((f4 % TPH) == 0) {
        int hh = f4 / TPH;
        esrc[n * HH + hh] = vs;
        edst[n * HH + hh] = vd;
    }
}

// ---------------- fused cnt (blocks 0..NBLK-1) + layer-1 GEMM (rest) ----------------
// cnt is latency-bound (gather + LDS atomics), gemm is VALU-bound; fat-kernel
// co-residency overlaps them: cost ~= max instead of sum.

__global__ __launch_bounds__(256) void cntgemm_kernel(
    const int* __restrict__ dst, int* __restrict__ cnt,
    const float* __restrict__ x, const float* __restrict__ W,
    const float* __restrict__ a_src, const float* __restrict__ a_dst,
    unsigned short* __restrict__ h, float* __restrict__ esrc,
    float* __restrict__ edst, int N) {
    __shared__ __align__(16) char smem[128 * 16 * 4];   // 8KB >= NBUC*4 (3128B)
    if (blockIdx.x < NBLK) {
        int* hh = (int*)smem;
        for (int i = threadIdx.x; i < NBUC; i += 256) hh[i] = 0;
        __syncthreads();
        int lo = blockIdx.x * EPB;
        int hi = lo + EPB; if (hi > ET) hi = ET;
        for (int k = lo + threadIdx.x; k < hi; k += 256) {
            int d = (k < NE) ? dst[k] : k - NE;   // self loops appended
            atomicAdd(&hh[d >> BSH], 1);
        }
        __syncthreads();
        int col = swz(blockIdx.x);
        for (int i = threadIdx.x; i < NBUC; i += 256)
            cnt[i * NBLK + col] = hh[i];
    } else {
        float* Ws = (float*)smem;
        for (int i = threadIdx.x; i < 128 * 16; i += 256) Ws[i] = W[i];
        __syncthreads();
        int idx = (blockIdx.x - NBLK) * 256 + threadIdx.x;
        gemm_attn_body<128, 16, 4>(idx, x, Ws, a_src, a_dst, h, esrc, edst, N);
    }
}

// ---------------- binned CSR build (rest) ----------------

__global__ __launch_bounds__(256) void rowsum_kernel(const int* __restrict__ cnt,
                                                     int* __restrict__ tot) {
    int wave = threadIdx.x >> 6, lane = threadIdx.x & 63;
    int b = blockIdx.x * 4 + wave;
    if (b >= NBUC) return;
    int4 v = ((const int4*)(cnt + b * NBLK))[lane];
    int s = v.x + v.y + v.z + v.w;
#pragma unroll
    for (int off = 32; off; off >>= 1) s += __shfl_xor(s, off);
    if (lane == 0) tot[b] = s;
}

__global__ __launch_bounds__(1024) void scan_kernel(const int* __restrict__ tot,
                                                    int* __restrict__ bstart) {
    __shared__ int t[1024];
    int b = threadIdx.x;
    int s = (b < NBUC) ? tot[b] : 0;
    t[b] = s;
    __syncthreads();
    for (int off = 1; off < 1024; off <<= 1) {
        int v = (b >= off) ? t[b - off] : 0;
        __syncthreads();
        t[b] += v;
        __syncthreads();
    }
    if (b < NBUC) bstart[b] = t[b] - s;
    if (b == 0) bstart[NBUC] = ET;
}

__global__ __launch_bounds__(256) void base_kernel(int* __restrict__ cnt,
                                                   const int* __restrict__ bstart) {
    int wave = threadIdx.x >> 6, lane = threadIdx.x & 63;
    int b = blockIdx.x * 4 + wave;
    if (b >= NBUC) return;
    int run = bstart[b];
    for (int c0 = 0; c0 < NBLK; c0 += 64) {
        int v = cnt[b * NBLK + c0 + lane];
        int x = v;
#pragma unroll
        for (int off = 1; off < 64; off <<= 1) {
            int y = __shfl_up(x, off);
            if (lane >= off) x += y;
        }
        cnt[b * NBLK + c0 + lane] = run + x - v;
        run += __shfl(x, 63);
    }
}

__global__ __launch_bounds__(1024) void scatter_kernel(const int* __restrict__ src,
                                                       const int* __restrict__ dst,
                                                       const int* __restrict__ base,
                                                       unsigned* __restrict__ tmpp) {
    __shared__ int loff[NBUC];
    int col = swz(blockIdx.x);
    for (int i = threadIdx.x; i < NBUC; i += 1024) loff[i] = base[i * NBLK + col];
    __syncthreads();
    int lo = blockIdx.x * EPB;
    int hi = lo + EPB; if (hi > ET) hi = ET;
    for (int k = lo + threadIdx.x; k < hi; k += 1024) {
        int s, d;
        if (k < NE) { s = src[k]; d = dst[k]; }
        else { s = d = k - NE; }
        int p = atomicAdd(&loff[d >> BSH], 1);
        tmpp[p] = (unsigned)s | ((unsigned)(d & (WIN - 1)) << 17);
    }
}

__global__ __launch_bounds__(1024) void sort_kernel(const int* __restrict__ bstart,
                                                    const unsigned* __restrict__ tmpp,
                                                    int* __restrict__ rowptr,
                                                    int* __restrict__ ssrc) {
    __shared__ int hist[WIN];
    __shared__ int scan[WIN];
    __shared__ int cur[WIN];
    int buc = blockIdx.x;
    int nlo = buc << BSH;
    int nwin = NN - nlo; if (nwin > WIN) nwin = WIN;
    int lo = bstart[buc], hi = bstart[buc + 1];
    int tid = threadIdx.x;
    if (tid < WIN) hist[tid] = 0;
    __syncthreads();
    for (int k = lo + tid; k < hi; k += 1024)
        atomicAdd(&hist[tmpp[k] >> 17], 1);
    __syncthreads();
    if (tid < WIN) scan[tid] = hist[tid];
    __syncthreads();
    for (int off = 1; off < WIN; off <<= 1) {
        int v = (tid >= off && tid < WIN) ? scan[tid - off] : 0;
        __syncthreads();
        if (tid < WIN) scan[tid] += v;
        __syncthreads();
    }
    if (tid < WIN) {
        int ex = scan[tid] - hist[tid];
        cur[tid] = ex;
        if (tid < nwin) rowptr[nlo + tid] = lo + ex;
    }
    if (buc == 0 && tid == 0) rowptr[NN] = ET;
    __syncthreads();
    for (int k = lo + tid; k < hi; k += 1024) {
        unsigned e = tmpp[k];
        int p = atomicAdd(&cur[e >> 17], 1);
        ssrc[lo + p] = (int)(e & 0x1FFFFu);
    }
}

// ---------------- standalone dense kernels ----------------

template <int FIN, int FOUT, int C>
__global__ __launch_bounds__(256) void gemm_attn_kernel(
    const float* __restrict__ x, const float* __restrict__ W,
    const float* __restrict__ a_src, const float* __restrict__ a_dst,
    unsigned short* __restrict__ h, float* __restrict__ esrc,
    float* __restrict__ edst, int N) {
    __shared__ __align__(16) float Ws[FIN * FOUT];
    for (int i = threadIdx.x; i < FIN * FOUT; i += blockDim.x) Ws[i] = W[i];
    __syncthreads();
    int idx = blockIdx.x * blockDim.x + threadIdx.x;
    gemm_attn_body<FIN, FOUT, C>(idx, x, Ws, a_src, a_dst, h, esrc, edst, N);
}

// plain GEMM with output row stride SO (shorts); layer 3: 40 feats at 80B rows
template <int FIN, int FOUT, int SO>
__global__ __launch_bounds__(256) void gemm_kernel(const float* __restrict__ x,
                                                   const float* __restrict__ W,
                                                   unsigned short* __restrict__ h, int N) {
    constexpr int F4 = FOUT / 4;
    __shared__ __align__(16) float Ws[FIN * FOUT];
    for (int i = threadIdx.x; i < FIN * FOUT; i += blockDim.x) Ws[i] = W[i];
    __syncthreads();
    int idx = blockIdx.x * blockDim.x + threadIdx.x;
    if (idx >= N * F4) return;
    int n = idx / F4, f4 = idx - n * F4;
    int fb = 4 * f4;
    const float4* xr = (const float4*)(x + (long)n * FIN);
    float a0 = 0.f, a1 = 0.f, a2 = 0.f, a3 = 0.f;
#pragma unroll
    for (int k4 = 0; k4 < FIN / 4; ++k4) {
        float4 xv = xr[k4];
        const float* wr = &Ws[(4 * k4) * FOUT + fb];
        float4 w0 = *(const float4*)(wr);
        float4 w1 = *(const float4*)(wr + FOUT);
        float4 w2 = *(const float4*)(wr + 2 * FOUT);
        float4 w3 = *(const float4*)(wr + 3 * FOUT);
        a0 = fmaf(xv.x, w0.x, a0); a1 = fmaf(xv.x, w0.y, a1);
        a2 = fmaf(xv.x, w0.z, a2); a3 = fmaf(xv.x, w0.w, a3);
        a0 = fmaf(xv.y, w1.x, a0); a1 = fmaf(xv.y, w1.y, a1);
        a2 = fmaf(xv.y, w1.z, a2); a3 = fmaf(xv.y, w1.w, a3);
        a0 = fmaf(xv.z, w2.x, a0); a1 = fmaf(xv.z, w2.y, a1);
        a2 = fmaf(xv.z, w2.z, a2); a3 = fmaf(xv.z, w2.w, a3);
        a0 = fmaf(xv.w, w3.x, a0); a1 = fmaf(xv.w, w3.y, a1);
        a2 = fmaf(xv.w, w3.z, a2); a3 = fmaf(xv.w, w3.w, a3);
    }
    *(ushort4*)(h + (long)n * SO + fb) = make_ushort4(f2bf(a0), f2bf(a1), f2bf(a2), f2bf(a3));
}

// attention logits for layer 3 (H=1), input row stride SO shorts, uint4 row read
template <int C, int SO>
__global__ void attn_kernel(const unsigned short* __restrict__ h,
                            const float* __restrict__ a_src,
                            const float* __restrict__ a_dst, float* __restrict__ esrc,
                            float* __restrict__ edst, int N) {
    int idx = blockIdx.x * blockDim.x + threadIdx.x;
    if (idx >= N) return;
    const uint4* hp = (const uint4*)(h + (long)idx * SO);
    float s = 0.f, d = 0.f;
#pragma unroll
    for (int c8 = 0; c8 < C / 8; ++c8) {
        uint4 v = hp[c8];
        int c = 8 * c8;
        s += bflo(v.x) * a_src[c] + bfhi(v.x) * a_src[c + 1];
        d += bflo(v.x) * a_dst[c] + bfhi(v.x) * a_dst[c + 1];
        s += bflo(v.y) * a_src[c + 2] + bfhi(v.y) * a_src[c + 3];
        d += bflo(v.y) * a_dst[c + 2] + bfhi(v.y) * a_dst[c + 3];
        s += bflo(v.z) * a_src[c + 4] + bfhi(v.z) * a_src[c + 5];
        d += bflo(v.z) * a_dst[c + 4] + bfhi(v.z) * a_dst[c + 5];
        s += bflo(v.w) * a_src[c + 6] + bfhi(v.w) * a_src[c + 7];
        d += bflo(v.w) * a_dst[c + 6] + bfhi(v.w) * a_dst[c + 7];
    }
    esrc[idx] = s;
    edst[idx] = d;
}

// ---------------- CSR gather aggregation ----------------
// Pipelined U-batches (issue all hv/es gathers + next ssrc before compute,
// pinned by sched_barrier). Tail folded via clamped indices + predicated ex.
// U=6: deeper memory-level parallelism toward the random-line BW ceiling.
template <int H, int C, int L, int G, int NPW, int FPL, int RSL, int U, bool ELU>
__global__ __launch_bounds__(256) void agg_kernel(
    const int* __restrict__ rowptr, const int* __restrict__ ssrc,
    const float* __restrict__ esrc, const float* __restrict__ edst,
    const unsigned short* __restrict__ hbuf, const float* __restrict__ b,
    float* __restrict__ out, int N) {
    constexpr int F = H * C;
    constexpr int AQ = (F + FPL - 1) / FPL;
    constexpr int S = L * G;
    static_assert(S * NPW == 64, "wave layout");
    static_assert(AQ <= L, "lanes cover features");
    int lane = threadIdx.x & 63;
    int wave = threadIdx.x >> 6;
    int sub = lane / S;
    int ls = lane - sub * S;
    int g = ls / L, q = ls - g * L;
    int n = (blockIdx.x * 4 + wave) * NPW + sub;
    if (n >= N) return;
    const bool act = (q < AQ);
    int h = act ? (FPL * q) / C : 0;
    int qa = act ? q : 0;
    float edn = edst[n * H + h];
    int beg = rowptr[n], end = rowptr[n + 1];
    int kend = end - 1;                   // deg >= 1 (self loop) -> always valid
    float sum = 0.f;
    float acc[FPL];
#pragma unroll
    for (int i = 0; i < FPL; ++i) acc[i] = 0.f;

    int k = beg + g;
    int ss[U];
#pragma unroll
    for (int u = 0; u < U; ++u) {
        int kk = k + u * G;
        ss[u] = ssrc[kk < kend ? kk : kend];
    }
    while (k < end) {
        uint4 hv4[U];
        uint2 hv2[U];
        float es[U];
#pragma unroll
        for (int u = 0; u < U; ++u) {
            if constexpr (FPL == 8) hv4[u] = ((const uint4*)hbuf)[ss[u] * RSL + qa];
            else hv2[u] = ((const uint2*)hbuf)[ss[u] * RSL + qa];
            es[u] = esrc[ss[u] * H + h];
        }
        int kn = k + U * G;
        int sn[U];
#pragma unroll
        for (int u = 0; u < U; ++u) {
            int kk = kn + u * G;
            sn[u] = ssrc[kk < kend ? kk : kend];
        }
        __builtin_amdgcn_sched_barrier(0);  // loads above must all issue first
#pragma unroll
        for (int u = 0; u < U; ++u) {
            float ex = (act && (k + u * G < end)) ? __expf(lrelu(es[u] + edn)) : 0.f;
            if constexpr (FPL == 8) {
                uint4 v = hv4[u];
                acc[0] = fmaf(ex, bflo(v.x), acc[0]); acc[1] = fmaf(ex, bfhi(v.x), acc[1]);
                acc[2] = fmaf(ex, bflo(v.y), acc[2]); acc[3] = fmaf(ex, bfhi(v.y), acc[3]);
                acc[4] = fmaf(ex, bflo(v.z), acc[4]); acc[5] = fmaf(ex, bfhi(v.z), acc[5]);
                acc[6] = fmaf(ex, bflo(v.w), acc[6]); acc[7] = fmaf(ex, bfhi(v.w), acc[7]);
            } else {
                uint2 v = hv2[u];
                acc[0] = fmaf(ex, bflo(v.x), acc[0]); acc[1] = fmaf(ex, bfhi(v.x), acc[1]);
                acc[2] = fmaf(ex, bflo(v.y), acc[2]); acc[3] = fmaf(ex, bfhi(v.y), acc[3]);
            }
            sum += ex;
        }
#pragma unroll
        for (int u = 0; u < U; ++u) ss[u] = sn[u];
        k = kn;
    }
#pragma unroll
    for (int step = L; step < S; step <<= 1) {
        sum += __shfl_xor(sum, step);
#pragma unroll
        for (int i = 0; i < FPL; ++i) acc[i] += __shfl_xor(acc[i], step);
    }
    if (g == 0 && act) {
        float inv = 1.f / (sum + 1e-16f);
        float v[FPL];
#pragma unroll
        for (int i = 0; i < FPL; ++i) {
            v[i] = acc[i] * inv + b[FPL * q + i];
            if (ELU) v[i] = v[i] > 0.f ? v[i] : __expf(v[i]) - 1.f;
        }
        float* op = out + n * F + FPL * q;
#pragma unroll
        for (int i = 0; i < FPL; i += 4)
            *(float4*)(op + i) = make_float4(v[i], v[i + 1], v[i + 2], v[i + 3]);
    }
}

static inline int cdiv(long a, int b) { return (int)((a + b - 1) / b); }

extern "C" void kernel_launch(void* const* d_in, const int* in_sizes, int n_in,
                              void* d_out, int out_size, void* d_ws, size_t ws_size,
                              hipStream_t stream) {
    const float* x1 = (const float*)d_in[0];
    const int* ei = (const int*)d_in[1];
    const int* src = ei;
    const int* dst = ei + NE;
    const float* W1 = (const float*)d_in[2];
    const float* as1 = (const float*)d_in[3];
    const float* ad1 = (const float*)d_in[4];
    const float* b1 = (const float*)d_in[5];
    const float* W2 = (const float*)d_in[6];
    const float* as2 = (const float*)d_in[7];
    const float* ad2 = (const float*)d_in[8];
    const float* b2 = (const float*)d_in[9];
    const float* W3 = (const float*)d_in[10];
    const float* as3 = (const float*)d_in[11];
    const float* ad3 = (const float*)d_in[12];
    const float* b3 = (const float*)d_in[13];
    float* out = (float*)d_out;

    // workspace carve (~80 MB)
    char* wsb = (char*)d_ws;
    unsigned short* hbuf = (unsigned short*)wsb;  wsb += (long)NN * 64 * 2;
    float* x2 = (float*)wsb;         wsb += (long)NN * 16 * 4;
    float* x3 = (float*)wsb;         wsb += (long)NN * 64 * 4;
    float* esrc = (float*)wsb;       wsb += (long)NN * 8 * 4;
    float* edst = (float*)wsb;       wsb += (long)NN * 8 * 4;
    unsigned* tmpp = (unsigned*)wsb; wsb += (long)ET * 4;
    int* ssrc = (int*)wsb;           wsb += (long)ET * 4;
    int* rowptr = (int*)wsb;         wsb += (long)(NN + 1) * 4;
    int* cnt = (int*)wsb;            wsb += (long)NBUC * NBLK * 4;
    int* bstart = (int*)wsb;         wsb += (long)(NBUC + 1) * 4;
    int* tot = (int*)wsb;            wsb += (long)NBUC * 4;

    const int B = 256;

    // ---- fused: CSR count (blocks 0..255) + layer-1 GEMM (rest) ----
    cntgemm_kernel<<<NBLK + cdiv((long)NN * 4, B), B, 0, stream>>>(
        dst, cnt, x1, W1, as1, ad1, hbuf, esrc, edst, NN);
    // ---- rest of CSR build ----
    rowsum_kernel<<<cdiv(NBUC, 4), B, 0, stream>>>(cnt, tot);
    scan_kernel<<<1, 1024, 0, stream>>>(tot, bstart);
    base_kernel<<<cdiv(NBUC, 4), B, 0, stream>>>(cnt, bstart);
    scatter_kernel<<<NBLK, 1024, 0, stream>>>(src, dst, cnt, tmpp);
    sort_kernel<<<NBUC, 1024, 0, stream>>>(bstart, tmpp, rowptr, ssrc);

    // ---- Layer 1 agg: H=4, C=4, ELU;  FPL=4, RSL=4, G=8, NPW=2, U=6 ----
    agg_kernel<4, 4, 4, 8, 2, 4, 4, 6, true><<<cdiv(NN, 8), B, 0, stream>>>(
        rowptr, ssrc, esrc, edst, hbuf, b1, x2, NN);

    // ---- Layer 2: 16 -> H=8, C=8 (concat 64), ELU;  FPL=8, RSL=8, G=8, U=6 ----
    gemm_attn_kernel<16, 64, 8><<<cdiv((long)NN * 16, B), B, 0, stream>>>(
        x2, W2, as2, ad2, hbuf, esrc, edst, NN);
    agg_kernel<8, 8, 8, 8, 1, 8, 8, 6, true><<<cdiv(NN, 4), B, 0, stream>>>(
        rowptr, ssrc, esrc, edst, hbuf, b2, x3, NN);

    // ---- Layer 3: 64 -> H=1, C=40, no concat, no ELU; rows packed at 80B (RSL=5) ----
    gemm_kernel<64, 40, 40><<<cdiv((long)NN * 10, B), B, 0, stream>>>(x3, W3, hbuf, NN);
    attn_kernel<40, 40><<<cdiv(NN, B), B, 0, stream>>>(hbuf, as3, ad3, esrc, edst, NN);
    agg_kernel<1, 40, 8, 8, 1, 8, 5, 6, false><<<cdiv(NN, 4), B, 0, stream>>>(
        rowptr, ssrc, esrc, edst, hbuf, b3, out, NN);
}

// Round 9
// 420.122 us; speedup vs baseline: 1.0243x; 1.0243x over previous
//
#include <hip/hip_runtime.h>

#define NN 100000
#define NE 3200000
#define ET (NE + NN)
#define NEG_SLOPE 0.2f
#define BSH 7
#define WIN (1 << BSH)                     // 128 nodes per bucket
#define NBUC ((NN + WIN - 1) >> BSH)       // 782 buckets
#define NBLK 256                           // scatter blocks (one per CU)
#define EPB ((ET + NBLK - 1) / NBLK)       // edges per scatter block

// XCD-swizzled region column: blocks b and b+8 (same XCD under round-robin
// dispatch) get adjacent columns -> each 128B cnt/tmpp line is produced by one
// XCD, written back once (round-5/6: 6.4x/15x write amplification otherwise).
__device__ __host__ __forceinline__ int swz(int b) {
    return (b & 7) * (NBLK / 8) + (b >> 3);
}

__device__ __forceinline__ float lrelu(float v) { return v > 0.f ? v : NEG_SLOPE * v; }

// bf16 <-> f32
__device__ __forceinline__ unsigned short f2bf(float x) {
    unsigned u = __float_as_uint(x);
    return (unsigned short)((u + 0x7fffu + ((u >> 16) & 1u)) >> 16);
}
__device__ __forceinline__ float bflo(unsigned u) { return __uint_as_float(u << 16); }
__device__ __forceinline__ float bfhi(unsigned u) { return __uint_as_float(u & 0xffff0000u); }

// packed 2xf32: maps to v_pk_fma_f32 on CDNA (2 FMA per instruction),
// bit-identical IEEE f32 fma per component.
typedef float f32x2 __attribute__((ext_vector_type(2)));
__device__ __forceinline__ f32x2 pkfma(f32x2 a, f32x2 b, f32x2 c) {
#if __has_builtin(__builtin_elementwise_fma)
    return __builtin_elementwise_fma(a, b, c);
#else
    f32x2 r; r.x = fmaf(a.x, b.x, c.x); r.y = fmaf(a.y, b.y, c.y); return r;
#endif
}
__device__ __forceinline__ f32x2 bfpair(unsigned u) {
    f32x2 r; r.x = bflo(u); r.y = bfhi(u); return r;
}

// ---------------- GEMM+attn body (shared by fused and standalone kernels) ----------------

template <int FIN, int FOUT, int C>
__device__ __forceinline__ void gemm_attn_body(
    int idx, const float* __restrict__ x, const float* Ws,
    const float* __restrict__ a_src, const float* __restrict__ a_dst,
    unsigned short* __restrict__ h, float* __restrict__ esrc,
    float* __restrict__ edst, int N) {
    constexpr int HH = FOUT / C;
    constexpr int F4 = FOUT / 4;
    constexpr int TPH = C / 4;           // threads per head
    if (idx >= N * F4) return;
    int n = idx / F4, f4 = idx - n * F4;
    int fb = 4 * f4;
    const float4* xr = (const float4*)(x + (long)n * FIN);
    float a0 = 0.f, a1 = 0.f, a2 = 0.f, a3 = 0.f;
#pragma unroll
    for (int k4 = 0; k4 < FIN / 4; ++k4) {
        float4 xv = xr[k4];
        const float* wr = &Ws[(4 * k4) * FOUT + fb];
        float4 w0 = *(const float4*)(wr);
        float4 w1 = *(const float4*)(wr + FOUT);
        float4 w2 = *(const float4*)(wr + 2 * FOUT);
        float4 w3 = *(const float4*)(wr + 3 * FOUT);
        a0 = fmaf(xv.x, w0.x, a0); a1 = fmaf(xv.x, w0.y, a1);
        a2 = fmaf(xv.x, w0.z, a2); a3 = fmaf(xv.x, w0.w, a3);
        a0 = fmaf(xv.y, w1.x, a0); a1 = fmaf(xv.y, w1.y, a1);
        a2 = fmaf(xv.y, w1.z, a2); a3 = fmaf(xv.y, w1.w, a3);
        a0 = fmaf(xv.z, w2.x, a0); a1 = fmaf(xv.z, w2.y, a1);
        a2 = fmaf(xv.z, w2.z, a2); a3 = fmaf(xv.z, w2.w, a3);
        a0 = fmaf(xv.w, w3.x, a0); a1 = fmaf(xv.w, w3.y, a1);
        a2 = fmaf(xv.w, w3.z, a2); a3 = fmaf(xv.w, w3.w, a3);
    }
    unsigned short b0 = f2bf(a0), b1 = f2bf(a1), b2 = f2bf(a2), b3 = f2bf(a3);
    *(ushort4*)(h + (long)n * FOUT + fb) = make_ushort4(b0, b1, b2, b3);
    float q0 = bflo((unsigned)b0), q1 = bflo((unsigned)b1);
    float q2 = bflo((unsigned)b2), q3 = bflo((unsigned)b3);
    float vs = q0 * a_src[fb] + q1 * a_src[fb + 1] + q2 * a_src[fb + 2] + q3 * a_src[fb + 3];
    float vd = q0 * a_dst[fb] + q1 * a_dst[fb + 1] + q2 * a_dst[fb + 2] + q3 * a_dst[fb + 3];
#pragma unroll
    for (int o = 1; o < TPH; o <<= 1) {
        vs += __shfl_xor(vs, o);
        vd += __shfl_xor(vd, o);
    }
    if ((f4 % TPH) == 0) {
        int hh = f4 / TPH;
        esrc[n * HH + hh] = vs;
        edst[n * HH + hh] = vd;
    }
}

// ---------------- fused cnt (blocks 0..NBLK-1) + layer-1 GEMM (rest) ----------------

__global__ __launch_bounds__(256) void cntgemm_kernel(
    const int* __restrict__ dst, int* __restrict__ cnt,
    const float* __restrict__ x, const float* __restrict__ W,
    const float* __restrict__ a_src, const float* __restrict__ a_dst,
    unsigned short* __restrict__ h, float* __restrict__ esrc,
    float* __restrict__ edst, int N) {
    __shared__ __align__(16) char smem[128 * 16 * 4];   // 8KB >= NBUC*4 (3128B)
    if (blockIdx.x < NBLK) {
        int* hh = (int*)smem;
        for (int i = threadIdx.x; i < NBUC; i += 256) hh[i] = 0;
        __syncthreads();
        int lo = blockIdx.x * EPB;
        int hi = lo + EPB; if (hi > ET) hi = ET;
        for (int k = lo + threadIdx.x; k < hi; k += 256) {
            int d = (k < NE) ? dst[k] : k - NE;   // self loops appended
            atomicAdd(&hh[d >> BSH], 1);
        }
        __syncthreads();
        int col = swz(blockIdx.x);
        for (int i = threadIdx.x; i < NBUC; i += 256)
            cnt[i * NBLK + col] = hh[i];
    } else {
        float* Ws = (float*)smem;
        for (int i = threadIdx.x; i < 128 * 16; i += 256) Ws[i] = W[i];
        __syncthreads();
        int idx = (blockIdx.x - NBLK) * 256 + threadIdx.x;
        gemm_attn_body<128, 16, 4>(idx, x, Ws, a_src, a_dst, h, esrc, edst, N);
    }
}

// ---------------- binned CSR build (rest) ----------------

__global__ __launch_bounds__(256) void rowsum_kernel(const int* __restrict__ cnt,
                                                     int* __restrict__ tot) {
    int wave = threadIdx.x >> 6, lane = threadIdx.x & 63;
    int b = blockIdx.x * 4 + wave;
    if (b >= NBUC) return;
    int4 v = ((const int4*)(cnt + b * NBLK))[lane];
    int s = v.x + v.y + v.z + v.w;
#pragma unroll
    for (int off = 32; off; off >>= 1) s += __shfl_xor(s, off);
    if (lane == 0) tot[b] = s;
}

__global__ __launch_bounds__(1024) void scan_kernel(const int* __restrict__ tot,
                                                    int* __restrict__ bstart) {
    __shared__ int t[1024];
    int b = threadIdx.x;
    int s = (b < NBUC) ? tot[b] : 0;
    t[b] = s;
    __syncthreads();
    for (int off = 1; off < 1024; off <<= 1) {
        int v = (b >= off) ? t[b - off] : 0;
        __syncthreads();
        t[b] += v;
        __syncthreads();
    }
    if (b < NBUC) bstart[b] = t[b] - s;
    if (b == 0) bstart[NBUC] = ET;
}

__global__ __launch_bounds__(256) void base_kernel(int* __restrict__ cnt,
                                                   const int* __restrict__ bstart) {
    int wave = threadIdx.x >> 6, lane = threadIdx.x & 63;
    int b = blockIdx.x * 4 + wave;
    if (b >= NBUC) return;
    int run = bstart[b];
    for (int c0 = 0; c0 < NBLK; c0 += 64) {
        int v = cnt[b * NBLK + c0 + lane];
        int x = v;
#pragma unroll
        for (int off = 1; off < 64; off <<= 1) {
            int y = __shfl_up(x, off);
            if (lane >= off) x += y;
        }
        cnt[b * NBLK + c0 + lane] = run + x - v;
        run += __shfl(x, 63);
    }
}

__global__ __launch_bounds__(1024) void scatter_kernel(const int* __restrict__ src,
                                                       const int* __restrict__ dst,
                                                       const int* __restrict__ base,
                                                       unsigned* __restrict__ tmpp) {
    __shared__ int loff[NBUC];
    int col = swz(blockIdx.x);
    for (int i = threadIdx.x; i < NBUC; i += 1024) loff[i] = base[i * NBLK + col];
    __syncthreads();
    int lo = blockIdx.x * EPB;
    int hi = lo + EPB; if (hi > ET) hi = ET;
    for (int k = lo + threadIdx.x; k < hi; k += 1024) {
        int s, d;
        if (k < NE) { s = src[k]; d = dst[k]; }
        else { s = d = k - NE; }
        int p = atomicAdd(&loff[d >> BSH], 1);
        tmpp[p] = (unsigned)s | ((unsigned)(d & (WIN - 1)) << 17);
    }
}

// sort: per-wave privatized histogram (16 waves x 128 counters) removes the
// LDS-atomic contention of 1024 threads on 128 counters; reduce after.
__global__ __launch_bounds__(1024) void sort_kernel(const int* __restrict__ bstart,
                                                    const unsigned* __restrict__ tmpp,
                                                    int* __restrict__ rowptr,
                                                    int* __restrict__ ssrc) {
    __shared__ int histw[16][WIN];
    __shared__ int scan[WIN];
    __shared__ int cur[WIN];
    int buc = blockIdx.x;
    int nlo = buc << BSH;
    int nwin = NN - nlo; if (nwin > WIN) nwin = WIN;
    int lo = bstart[buc], hi = bstart[buc + 1];
    int tid = threadIdx.x;
    int wv = tid >> 6;
    for (int i = tid; i < 16 * WIN; i += 1024) ((int*)histw)[i] = 0;
    __syncthreads();
    for (int k = lo + tid; k < hi; k += 1024)
        atomicAdd(&histw[wv][tmpp[k] >> 17], 1);
    __syncthreads();
    int myh = 0;
    if (tid < WIN) {
        int s = 0;
#pragma unroll
        for (int w = 0; w < 16; ++w) s += histw[w][tid];
        myh = s;
        scan[tid] = s;
    }
    __syncthreads();
    for (int off = 1; off < WIN; off <<= 1) {
        int v = (tid >= off && tid < WIN) ? scan[tid - off] : 0;
        __syncthreads();
        if (tid < WIN) scan[tid] += v;
        __syncthreads();
    }
    if (tid < WIN) {
        int ex = scan[tid] - myh;
        cur[tid] = ex;
        if (tid < nwin) rowptr[nlo + tid] = lo + ex;
    }
    if (buc == 0 && tid == 0) rowptr[NN] = ET;
    __syncthreads();
    for (int k = lo + tid; k < hi; k += 1024) {
        unsigned e = tmpp[k];
        int p = atomicAdd(&cur[e >> 17], 1);
        ssrc[lo + p] = (int)(e & 0x1FFFFu);
    }
}

// ---------------- standalone dense kernels ----------------

template <int FIN, int FOUT, int C>
__global__ __launch_bounds__(256) void gemm_attn_kernel(
    const float* __restrict__ x, const float* __restrict__ W,
    const float* __restrict__ a_src, const float* __restrict__ a_dst,
    unsigned short* __restrict__ h, float* __restrict__ esrc,
    float* __restrict__ edst, int N) {
    __shared__ __align__(16) float Ws[FIN * FOUT];
    for (int i = threadIdx.x; i < FIN * FOUT; i += blockDim.x) Ws[i] = W[i];
    __syncthreads();
    int idx = blockIdx.x * blockDim.x + threadIdx.x;
    gemm_attn_body<FIN, FOUT, C>(idx, x, Ws, a_src, a_dst, h, esrc, edst, N);
}

// plain GEMM with output row stride SO (shorts); layer 3: 40 feats at 80B rows
template <int FIN, int FOUT, int SO>
__global__ __launch_bounds__(256) void gemm_kernel(const float* __restrict__ x,
                                                   const float* __restrict__ W,
                                                   unsigned short* __restrict__ h, int N) {
    constexpr int F4 = FOUT / 4;
    __shared__ __align__(16) float Ws[FIN * FOUT];
    for (int i = threadIdx.x; i < FIN * FOUT; i += blockDim.x) Ws[i] = W[i];
    __syncthreads();
    int idx = blockIdx.x * blockDim.x + threadIdx.x;
    if (idx >= N * F4) return;
    int n = idx / F4, f4 = idx - n * F4;
    int fb = 4 * f4;
    const float4* xr = (const float4*)(x + (long)n * FIN);
    float a0 = 0.f, a1 = 0.f, a2 = 0.f, a3 = 0.f;
#pragma unroll
    for (int k4 = 0; k4 < FIN / 4; ++k4) {
        float4 xv = xr[k4];
        const float* wr = &Ws[(4 * k4) * FOUT + fb];
        float4 w0 = *(const float4*)(wr);
        float4 w1 = *(const float4*)(wr + FOUT);
        float4 w2 = *(const float4*)(wr + 2 * FOUT);
        float4 w3 = *(const float4*)(wr + 3 * FOUT);
        a0 = fmaf(xv.x, w0.x, a0); a1 = fmaf(xv.x, w0.y, a1);
        a2 = fmaf(xv.x, w0.z, a2); a3 = fmaf(xv.x, w0.w, a3);
        a0 = fmaf(xv.y, w1.x, a0); a1 = fmaf(xv.y, w1.y, a1);
        a2 = fmaf(xv.y, w1.z, a2); a3 = fmaf(xv.y, w1.w, a3);
        a0 = fmaf(xv.z, w2.x, a0); a1 = fmaf(xv.z, w2.y, a1);
        a2 = fmaf(xv.z, w2.z, a2); a3 = fmaf(xv.z, w2.w, a3);
        a0 = fmaf(xv.w, w3.x, a0); a1 = fmaf(xv.w, w3.y, a1);
        a2 = fmaf(xv.w, w3.z, a2); a3 = fmaf(xv.w, w3.w, a3);
    }
    *(ushort4*)(h + (long)n * SO + fb) = make_ushort4(f2bf(a0), f2bf(a1), f2bf(a2), f2bf(a3));
}

// attention logits for layer 3 (H=1), input row stride SO shorts, uint4 row read
template <int C, int SO>
__global__ void attn_kernel(const unsigned short* __restrict__ h,
                            const float* __restrict__ a_src,
                            const float* __restrict__ a_dst, float* __restrict__ esrc,
                            float* __restrict__ edst, int N) {
    int idx = blockIdx.x * blockDim.x + threadIdx.x;
    if (idx >= N) return;
    const uint4* hp = (const uint4*)(h + (long)idx * SO);
    float s = 0.f, d = 0.f;
#pragma unroll
    for (int c8 = 0; c8 < C / 8; ++c8) {
        uint4 v = hp[c8];
        int c = 8 * c8;
        s += bflo(v.x) * a_src[c] + bfhi(v.x) * a_src[c + 1];
        d += bflo(v.x) * a_dst[c] + bfhi(v.x) * a_dst[c + 1];
        s += bflo(v.y) * a_src[c + 2] + bfhi(v.y) * a_src[c + 3];
        d += bflo(v.y) * a_dst[c + 2] + bfhi(v.y) * a_dst[c + 3];
        s += bflo(v.z) * a_src[c + 4] + bfhi(v.z) * a_src[c + 5];
        d += bflo(v.z) * a_dst[c + 4] + bfhi(v.z) * a_dst[c + 5];
        s += bflo(v.w) * a_src[c + 6] + bfhi(v.w) * a_src[c + 7];
        d += bflo(v.w) * a_dst[c + 6] + bfhi(v.w) * a_dst[c + 7];
    }
    esrc[idx] = s;
    edst[idx] = d;
}

// ---------------- CSR gather aggregation ----------------
// Pipelined U-batches (issue all hv/es gathers + next ssrc before compute,
// pinned by sched_barrier). Tail folded via clamped indices + predicated ex.
// Accumulate via packed f32 fma (v_pk_fma_f32): 2 features per VALU op.
template <int H, int C, int L, int G, int NPW, int FPL, int RSL, int U, bool ELU>
__global__ __launch_bounds__(256) void agg_kernel(
    const int* __restrict__ rowptr, const int* __restrict__ ssrc,
    const float* __restrict__ esrc, const float* __restrict__ edst,
    const unsigned short* __restrict__ hbuf, const float* __restrict__ b,
    float* __restrict__ out, int N) {
    constexpr int F = H * C;
    constexpr int AQ = (F + FPL - 1) / FPL;
    constexpr int S = L * G;
    constexpr int P = FPL / 2;           // f32x2 accumulators
    static_assert(S * NPW == 64, "wave layout");
    static_assert(AQ <= L, "lanes cover features");
    int lane = threadIdx.x & 63;
    int wave = threadIdx.x >> 6;
    int sub = lane / S;
    int ls = lane - sub * S;
    int g = ls / L, q = ls - g * L;
    int n = (blockIdx.x * 4 + wave) * NPW + sub;
    if (n >= N) return;
    const bool act = (q < AQ);
    int h = act ? (FPL * q) / C : 0;
    int qa = act ? q : 0;
    float edn = edst[n * H + h];
    int beg = rowptr[n], end = rowptr[n + 1];
    int kend = end - 1;                   // deg >= 1 (self loop) -> always valid
    float sum = 0.f;
    f32x2 acc[P];
#pragma unroll
    for (int i = 0; i < P; ++i) { acc[i].x = 0.f; acc[i].y = 0.f; }

    int k = beg + g;
    int ss[U];
#pragma unroll
    for (int u = 0; u < U; ++u) {
        int kk = k + u * G;
        ss[u] = ssrc[kk < kend ? kk : kend];
    }
    while (k < end) {
        uint4 hv4[U];
        uint2 hv2[U];
        float es[U];
#pragma unroll
        for (int u = 0; u < U; ++u) {
            if constexpr (FPL == 8) hv4[u] = ((const uint4*)hbuf)[ss[u] * RSL + qa];
            else hv2[u] = ((const uint2*)hbuf)[ss[u] * RSL + qa];
            es[u] = esrc[ss[u] * H + h];
        }
        int kn = k + U * G;
        int sn[U];
#pragma unroll
        for (int u = 0; u < U; ++u) {
            int kk = kn + u * G;
            sn[u] = ssrc[kk < kend ? kk : kend];
        }
        __builtin_amdgcn_sched_barrier(0);  // loads above must all issue first
#pragma unroll
        for (int u = 0; u < U; ++u) {
            float ex = (act && (k + u * G < end)) ? __expf(lrelu(es[u] + edn)) : 0.f;
            f32x2 exv; exv.x = ex; exv.y = ex;
            if constexpr (FPL == 8) {
                uint4 v = hv4[u];
                acc[0] = pkfma(exv, bfpair(v.x), acc[0]);
                acc[1] = pkfma(exv, bfpair(v.y), acc[1]);
                acc[2] = pkfma(exv, bfpair(v.z), acc[2]);
                acc[3] = pkfma(exv, bfpair(v.w), acc[3]);
            } else {
                uint2 v = hv2[u];
                acc[0] = pkfma(exv, bfpair(v.x), acc[0]);
                acc[1] = pkfma(exv, bfpair(v.y), acc[1]);
            }
            sum += ex;
        }
#pragma unroll
        for (int u = 0; u < U; ++u) ss[u] = sn[u];
        k = kn;
    }
#pragma unroll
    for (int step = L; step < S; step <<= 1) {
        sum += __shfl_xor(sum, step);
#pragma unroll
        for (int i = 0; i < P; ++i) {
            acc[i].x += __shfl_xor(acc[i].x, step);
            acc[i].y += __shfl_xor(acc[i].y, step);
        }
    }
    if (g == 0 && act) {
        float inv = 1.f / (sum + 1e-16f);
        float v[FPL];
#pragma unroll
        for (int i = 0; i < FPL; ++i) {
            float av = (i & 1) ? acc[i >> 1].y : acc[i >> 1].x;
            v[i] = av * inv + b[FPL * q + i];
            if (ELU) v[i] = v[i] > 0.f ? v[i] : __expf(v[i]) - 1.f;
        }
        float* op = out + n * F + FPL * q;
#pragma unroll
        for (int i = 0; i < FPL; i += 4)
            *(float4*)(op + i) = make_float4(v[i], v[i + 1], v[i + 2], v[i + 3]);
    }
}

static inline int cdiv(long a, int b) { return (int)((a + b - 1) / b); }

extern "C" void kernel_launch(void* const* d_in, const int* in_sizes, int n_in,
                              void* d_out, int out_size, void* d_ws, size_t ws_size,
                              hipStream_t stream) {
    const float* x1 = (const float*)d_in[0];
    const int* ei = (const int*)d_in[1];
    const int* src = ei;
    const int* dst = ei + NE;
    const float* W1 = (const float*)d_in[2];
    const float* as1 = (const float*)d_in[3];
    const float* ad1 = (const float*)d_in[4];
    const float* b1 = (const float*)d_in[5];
    const float* W2 = (const float*)d_in[6];
    const float* as2 = (const float*)d_in[7];
    const float* ad2 = (const float*)d_in[8];
    const float* b2 = (const float*)d_in[9];
    const float* W3 = (const float*)d_in[10];
    const float* as3 = (const float*)d_in[11];
    const float* ad3 = (const float*)d_in[12];
    const float* b3 = (const float*)d_in[13];
    float* out = (float*)d_out;

    // workspace carve (~80 MB)
    char* wsb = (char*)d_ws;
    unsigned short* hbuf = (unsigned short*)wsb;  wsb += (long)NN * 64 * 2;
    float* x2 = (float*)wsb;         wsb += (long)NN * 16 * 4;
    float* x3 = (float*)wsb;         wsb += (long)NN * 64 * 4;
    float* esrc = (float*)wsb;       wsb += (long)NN * 8 * 4;
    float* edst = (float*)wsb;       wsb += (long)NN * 8 * 4;
    unsigned* tmpp = (unsigned*)wsb; wsb += (long)ET * 4;
    int* ssrc = (int*)wsb;           wsb += (long)ET * 4;
    int* rowptr = (int*)wsb;         wsb += (long)(NN + 1) * 4;
    int* cnt = (int*)wsb;            wsb += (long)NBUC * NBLK * 4;
    int* bstart = (int*)wsb;         wsb += (long)(NBUC + 1) * 4;
    int* tot = (int*)wsb;            wsb += (long)NBUC * 4;

    const int B = 256;

    // ---- fused: CSR count (blocks 0..255) + layer-1 GEMM (rest) ----
    cntgemm_kernel<<<NBLK + cdiv((long)NN * 4, B), B, 0, stream>>>(
        dst, cnt, x1, W1, as1, ad1, hbuf, esrc, edst, NN);
    // ---- rest of CSR build ----
    rowsum_kernel<<<cdiv(NBUC, 4), B, 0, stream>>>(cnt, tot);
    scan_kernel<<<1, 1024, 0, stream>>>(tot, bstart);
    base_kernel<<<cdiv(NBUC, 4), B, 0, stream>>>(cnt, bstart);
    scatter_kernel<<<NBLK, 1024, 0, stream>>>(src, dst, cnt, tmpp);
    sort_kernel<<<NBUC, 1024, 0, stream>>>(bstart, tmpp, rowptr, ssrc);

    // ---- Layer 1 agg: H=4, C=4, ELU;  FPL=4, RSL=4, G=8, NPW=2, U=5 ----
    agg_kernel<4, 4, 4, 8, 2, 4, 4, 5, true><<<cdiv(NN, 8), B, 0, stream>>>(
        rowptr, ssrc, esrc, edst, hbuf, b1, x2, NN);

    // ---- Layer 2: 16 -> H=8, C=8 (concat 64), ELU;  FPL=8, RSL=8, G=8, U=5 ----
    gemm_attn_kernel<16, 64, 8><<<cdiv((long)NN * 16, B), B, 0, stream>>>(
        x2, W2, as2, ad2, hbuf, esrc, edst, NN);
    agg_kernel<8, 8, 8, 8, 1, 8, 8, 5, true><<<cdiv(NN, 4), B, 0, stream>>>(
        rowptr, ssrc, esrc, edst, hbuf, b2, x3, NN);

    // ---- Layer 3: 64 -> H=1, C=40, no concat, no ELU; rows packed at 80B (RSL=5) ----
    gemm_kernel<64, 40, 40><<<cdiv((long)NN * 10, B), B, 0, stream>>>(x3, W3, hbuf, NN);
    attn_kernel<40, 40><<<cdiv(NN, B), B, 0, stream>>>(hbuf, as3, ad3, esrc, edst, NN);
    agg_kernel<1, 40, 8, 8, 1, 8, 5, 5, false><<<cdiv(NN, 4), B, 0, stream>>>(
        rowptr, ssrc, esrc, edst, hbuf, b3, out, NN);
}

// Round 10
// 418.572 us; speedup vs baseline: 1.0281x; 1.0037x over previous
//
#include <hip/hip_runtime.h>

#define NN 100000
#define NE 3200000
#define ET (NE + NN)
#define NEG_SLOPE 0.2f
#define BSH 8
#define WIN (1 << BSH)                     // 256 nodes per bucket
#define NBUC ((NN + WIN - 1) >> BSH)       // 391 buckets
#define NBLK 256                           // scatter blocks (one per CU)
#define EPB ((ET + NBLK - 1) / NBLK)       // edges per scatter block

// XCD-swizzled region column: blocks b and b+8 (same XCD under round-robin
// dispatch) get adjacent columns -> each 128B cnt/tmpp line is produced by one
// XCD, written back once (round-5/6: 6.4x/15x write amplification otherwise).
__device__ __host__ __forceinline__ int swz(int b) {
    return (b & 7) * (NBLK / 8) + (b >> 3);
}

__device__ __forceinline__ float lrelu(float v) { return v > 0.f ? v : NEG_SLOPE * v; }

// bf16 <-> f32
__device__ __forceinline__ unsigned short f2bf(float x) {
    unsigned u = __float_as_uint(x);
    return (unsigned short)((u + 0x7fffu + ((u >> 16) & 1u)) >> 16);
}
__device__ __forceinline__ float bflo(unsigned u) { return __uint_as_float(u << 16); }
__device__ __forceinline__ float bfhi(unsigned u) { return __uint_as_float(u & 0xffff0000u); }

// packed 2xf32 -> v_pk_fma_f32 (bit-identical IEEE fma per component)
typedef float f32x2 __attribute__((ext_vector_type(2)));
__device__ __forceinline__ f32x2 pkfma(f32x2 a, f32x2 b, f32x2 c) {
#if __has_builtin(__builtin_elementwise_fma)
    return __builtin_elementwise_fma(a, b, c);
#else
    f32x2 r; r.x = fmaf(a.x, b.x, c.x); r.y = fmaf(a.y, b.y, c.y); return r;
#endif
}
__device__ __forceinline__ f32x2 bfpair(unsigned u) {
    f32x2 r; r.x = bflo(u); r.y = bfhi(u); return r;
}

// ---------------- GEMM+attn body (shared by fused and standalone kernels) ----------------

template <int FIN, int FOUT, int C>
__device__ __forceinline__ void gemm_attn_body(
    int idx, const float* __restrict__ x, const float* Ws,
    const float* __restrict__ a_src, const float* __restrict__ a_dst,
    unsigned short* __restrict__ h, float* __restrict__ esrc,
    float* __restrict__ edst, int N) {
    constexpr int HH = FOUT / C;
    constexpr int F4 = FOUT / 4;
    constexpr int TPH = C / 4;           // threads per head
    if (idx >= N * F4) return;
    int n = idx / F4, f4 = idx - n * F4;
    int fb = 4 * f4;
    const float4* xr = (const float4*)(x + (long)n * FIN);
    float a0 = 0.f, a1 = 0.f, a2 = 0.f, a3 = 0.f;
#pragma unroll
    for (int k4 = 0; k4 < FIN / 4; ++k4) {
        float4 xv = xr[k4];
        const float* wr = &Ws[(4 * k4) * FOUT + fb];
        float4 w0 = *(const float4*)(wr);
        float4 w1 = *(const float4*)(wr + FOUT);
        float4 w2 = *(const float4*)(wr + 2 * FOUT);
        float4 w3 = *(const float4*)(wr + 3 * FOUT);
        a0 = fmaf(xv.x, w0.x, a0); a1 = fmaf(xv.x, w0.y, a1);
        a2 = fmaf(xv.x, w0.z, a2); a3 = fmaf(xv.x, w0.w, a3);
        a0 = fmaf(xv.y, w1.x, a0); a1 = fmaf(xv.y, w1.y, a1);
        a2 = fmaf(xv.y, w1.z, a2); a3 = fmaf(xv.y, w1.w, a3);
        a0 = fmaf(xv.z, w2.x, a0); a1 = fmaf(xv.z, w2.y, a1);
        a2 = fmaf(xv.z, w2.z, a2); a3 = fmaf(xv.z, w2.w, a3);
        a0 = fmaf(xv.w, w3.x, a0); a1 = fmaf(xv.w, w3.y, a1);
        a2 = fmaf(xv.w, w3.z, a2); a3 = fmaf(xv.w, w3.w, a3);
    }
    unsigned short b0 = f2bf(a0), b1 = f2bf(a1), b2 = f2bf(a2), b3 = f2bf(a3);
    *(ushort4*)(h + (long)n * FOUT + fb) = make_ushort4(b0, b1, b2, b3);
    float q0 = bflo((unsigned)b0), q1 = bflo((unsigned)b1);
    float q2 = bflo((unsigned)b2), q3 = bflo((unsigned)b3);
    float vs = q0 * a_src[fb] + q1 * a_src[fb + 1] + q2 * a_src[fb + 2] + q3 * a_src[fb + 3];
    float vd = q0 * a_dst[fb] + q1 * a_dst[fb + 1] + q2 * a_dst[fb + 2] + q3 * a_dst[fb + 3];
#pragma unroll
    for (int o = 1; o < TPH; o <<= 1) {
        vs += __shfl_xor(vs, o);
        vd += __shfl_xor(vd, o);
    }
    if ((f4 % TPH) == 0) {
        int hh = f4 / TPH;
        esrc[n * HH + hh] = vs;
        edst[n * HH + hh] = vd;
    }
}

// ---------------- fused cnt (blocks 0..NBLK-1) + layer-1 GEMM (rest) ----------------

__global__ __launch_bounds__(256) void cntgemm_kernel(
    const int* __restrict__ dst, int* __restrict__ cnt,
    const float* __restrict__ x, const float* __restrict__ W,
    const float* __restrict__ a_src, const float* __restrict__ a_dst,
    unsigned short* __restrict__ h, float* __restrict__ esrc,
    float* __restrict__ edst, int N) {
    __shared__ __align__(16) char smem[128 * 16 * 4];   // 8KB >= NBUC*4 (1564B)
    if (blockIdx.x < NBLK) {
        int* hh = (int*)smem;
        for (int i = threadIdx.x; i < NBUC; i += 256) hh[i] = 0;
        __syncthreads();
        int lo = blockIdx.x * EPB;
        int hi = lo + EPB; if (hi > ET) hi = ET;
        for (int k = lo + threadIdx.x; k < hi; k += 256) {
            int d = (k < NE) ? dst[k] : k - NE;   // self loops appended
            atomicAdd(&hh[d >> BSH], 1);
        }
        __syncthreads();
        int col = swz(blockIdx.x);
        for (int i = threadIdx.x; i < NBUC; i += 256)
            cnt[i * NBLK + col] = hh[i];
    } else {
        float* Ws = (float*)smem;
        for (int i = threadIdx.x; i < 128 * 16; i += 256) Ws[i] = W[i];
        __syncthreads();
        int idx = (blockIdx.x - NBLK) * 256 + threadIdx.x;
        gemm_attn_body<128, 16, 4>(idx, x, Ws, a_src, a_dst, h, esrc, edst, N);
    }
}

// ---------------- binned CSR build (rest) ----------------

__global__ __launch_bounds__(256) void rowsum_kernel(const int* __restrict__ cnt,
                                                     int* __restrict__ tot) {
    int wave = threadIdx.x >> 6, lane = threadIdx.x & 63;
    int b = blockIdx.x * 4 + wave;
    if (b >= NBUC) return;
    int4 v = ((const int4*)(cnt + b * NBLK))[lane];
    int s = v.x + v.y + v.z + v.w;
#pragma unroll
    for (int off = 32; off; off >>= 1) s += __shfl_xor(s, off);
    if (lane == 0) tot[b] = s;
}

__global__ __launch_bounds__(1024) void scan_kernel(const int* __restrict__ tot,
                                                    int* __restrict__ bstart) {
    __shared__ int t[1024];
    int b = threadIdx.x;
    int s = (b < NBUC) ? tot[b] : 0;
    t[b] = s;
    __syncthreads();
    for (int off = 1; off < 1024; off <<= 1) {
        int v = (b >= off) ? t[b - off] : 0;
        __syncthreads();
        t[b] += v;
        __syncthreads();
    }
    if (b < NBUC) bstart[b] = t[b] - s;
    if (b == 0) bstart[NBUC] = ET;
}

__global__ __launch_bounds__(256) void base_kernel(int* __restrict__ cnt,
                                                   const int* __restrict__ bstart) {
    int wave = threadIdx.x >> 6, lane = threadIdx.x & 63;
    int b = blockIdx.x * 4 + wave;
    if (b >= NBUC) return;
    int run = bstart[b];
    for (int c0 = 0; c0 < NBLK; c0 += 64) {
        int v = cnt[b * NBLK + c0 + lane];
        int x = v;
#pragma unroll
        for (int off = 1; off < 64; off <<= 1) {
            int y = __shfl_up(x, off);
            if (lane >= off) x += y;
        }
        cnt[b * NBLK + c0 + lane] = run + x - v;
        run += __shfl(x, 63);
    }
}

__global__ __launch_bounds__(1024) void scatter_kernel(const int* __restrict__ src,
                                                       const int* __restrict__ dst,
                                                       const int* __restrict__ base,
                                                       unsigned* __restrict__ tmpp) {
    __shared__ int loff[NBUC];
    int col = swz(blockIdx.x);
    for (int i = threadIdx.x; i < NBUC; i += 1024) loff[i] = base[i * NBLK + col];
    __syncthreads();
    int lo = blockIdx.x * EPB;
    int hi = lo + EPB; if (hi > ET) hi = ET;
    for (int k = lo + threadIdx.x; k < hi; k += 1024) {
        int s, d;
        if (k < NE) { s = src[k]; d = dst[k]; }
        else { s = d = k - NE; }
        int p = atomicAdd(&loff[d >> BSH], 1);
        tmpp[p] = (unsigned)s | ((unsigned)(d & (WIN - 1)) << 17);
    }
}

// sort: per-wave privatized histogram (16 waves x WIN counters)
__global__ __launch_bounds__(1024) void sort_kernel(const int* __restrict__ bstart,
                                                    const unsigned* __restrict__ tmpp,
                                                    int* __restrict__ rowptr,
                                                    int* __restrict__ ssrc) {
    __shared__ int histw[16][WIN];
    __shared__ int scan[WIN];
    __shared__ int cur[WIN];
    int buc = blockIdx.x;
    int nlo = buc << BSH;
    int nwin = NN - nlo; if (nwin > WIN) nwin = WIN;
    int lo = bstart[buc], hi = bstart[buc + 1];
    int tid = threadIdx.x;
    int wv = tid >> 6;
    for (int i = tid; i < 16 * WIN; i += 1024) ((int*)histw)[i] = 0;
    __syncthreads();
    for (int k = lo + tid; k < hi; k += 1024)
        atomicAdd(&histw[wv][tmpp[k] >> 17], 1);
    __syncthreads();
    int myh = 0;
    if (tid < WIN) {
        int s = 0;
#pragma unroll
        for (int w = 0; w < 16; ++w) s += histw[w][tid];
        myh = s;
        scan[tid] = s;
    }
    __syncthreads();
    for (int off = 1; off < WIN; off <<= 1) {
        int v = (tid >= off && tid < WIN) ? scan[tid - off] : 0;
        __syncthreads();
        if (tid < WIN) scan[tid] += v;
        __syncthreads();
    }
    if (tid < WIN) {
        int ex = scan[tid] - myh;
        cur[tid] = ex;
        if (tid < nwin) rowptr[nlo + tid] = lo + ex;
    }
    if (buc == 0 && tid == 0) rowptr[NN] = ET;
    __syncthreads();
    for (int k = lo + tid; k < hi; k += 1024) {
        unsigned e = tmpp[k];
        int p = atomicAdd(&cur[e >> 17], 1);
        ssrc[lo + p] = (int)(e & 0x1FFFFu);
    }
}

// ---------------- standalone dense kernels ----------------

template <int FIN, int FOUT, int C>
__global__ __launch_bounds__(256) void gemm_attn_kernel(
    const float* __restrict__ x, const float* __restrict__ W,
    const float* __restrict__ a_src, const float* __restrict__ a_dst,
    unsigned short* __restrict__ h, float* __restrict__ esrc,
    float* __restrict__ edst, int N) {
    __shared__ __align__(16) float Ws[FIN * FOUT];
    for (int i = threadIdx.x; i < FIN * FOUT; i += blockDim.x) Ws[i] = W[i];
    __syncthreads();
    int idx = blockIdx.x * blockDim.x + threadIdx.x;
    gemm_attn_body<FIN, FOUT, C>(idx, x, Ws, a_src, a_dst, h, esrc, edst, N);
}

// layer-3 GEMM fused with its H=1 attention logits. Block = 320 threads = exactly
// 32 nodes x 10 threads (no node straddles a block); per-thread partials reduced
// in LDS in ascending-feature order.
__global__ __launch_bounds__(320) void gemm_attn3_kernel(
    const float* __restrict__ x, const float* __restrict__ W,
    const float* __restrict__ a_src, const float* __restrict__ a_dst,
    unsigned short* __restrict__ h, float* __restrict__ esrc,
    float* __restrict__ edst, int N) {
    constexpr int FIN = 64, FOUT = 40, F4 = 10;
    __shared__ __align__(16) float Ws[FIN * FOUT];
    __shared__ float ps[320], pd[320];
    int tid = threadIdx.x;
    for (int i = tid; i < FIN * FOUT; i += 320) Ws[i] = W[i];
    __syncthreads();
    int idx = blockIdx.x * 320 + tid;
    int n = idx / F4, f4 = idx - n * F4;
    float vs = 0.f, vd = 0.f;
    if (n < N) {
        int fb = 4 * f4;
        const float4* xr = (const float4*)(x + (long)n * FIN);
        float a0 = 0.f, a1 = 0.f, a2 = 0.f, a3 = 0.f;
#pragma unroll
        for (int k4 = 0; k4 < FIN / 4; ++k4) {
            float4 xv = xr[k4];
            const float* wr = &Ws[(4 * k4) * FOUT + fb];
            float4 w0 = *(const float4*)(wr);
            float4 w1 = *(const float4*)(wr + FOUT);
            float4 w2 = *(const float4*)(wr + 2 * FOUT);
            float4 w3 = *(const float4*)(wr + 3 * FOUT);
            a0 = fmaf(xv.x, w0.x, a0); a1 = fmaf(xv.x, w0.y, a1);
            a2 = fmaf(xv.x, w0.z, a2); a3 = fmaf(xv.x, w0.w, a3);
            a0 = fmaf(xv.y, w1.x, a0); a1 = fmaf(xv.y, w1.y, a1);
            a2 = fmaf(xv.y, w1.z, a2); a3 = fmaf(xv.y, w1.w, a3);
            a0 = fmaf(xv.z, w2.x, a0); a1 = fmaf(xv.z, w2.y, a1);
            a2 = fmaf(xv.z, w2.z, a2); a3 = fmaf(xv.z, w2.w, a3);
            a0 = fmaf(xv.w, w3.x, a0); a1 = fmaf(xv.w, w3.y, a1);
            a2 = fmaf(xv.w, w3.z, a2); a3 = fmaf(xv.w, w3.w, a3);
        }
        unsigned short b0 = f2bf(a0), b1 = f2bf(a1), b2 = f2bf(a2), b3 = f2bf(a3);
        *(ushort4*)(h + (long)n * FOUT + fb) = make_ushort4(b0, b1, b2, b3);
        float q0 = bflo((unsigned)b0), q1 = bflo((unsigned)b1);
        float q2 = bflo((unsigned)b2), q3 = bflo((unsigned)b3);
        vs = q0 * a_src[fb] + q1 * a_src[fb + 1] + q2 * a_src[fb + 2] + q3 * a_src[fb + 3];
        vd = q0 * a_dst[fb] + q1 * a_dst[fb + 1] + q2 * a_dst[fb + 2] + q3 * a_dst[fb + 3];
    }
    ps[tid] = vs; pd[tid] = vd;
    __syncthreads();
    if (tid < 32) {
        int n0 = blockIdx.x * 32 + tid;
        if (n0 < N) {
            float s = 0.f, d = 0.f;
#pragma unroll
            for (int j = 0; j < F4; ++j) { s += ps[tid * F4 + j]; d += pd[tid * F4 + j]; }
            esrc[n0] = s;
            edst[n0] = d;
        }
    }
}

// ---------------- CSR gather aggregation ----------------
// Pipelined U-batches (issue all hv/es gathers + next ssrc before compute,
// pinned by sched_barrier). Tail folded via clamped indices + predicated ex.
// Accumulate via packed f32 fma (v_pk_fma_f32).
template <int H, int C, int L, int G, int NPW, int FPL, int RSL, int U, bool ELU>
__device__ __forceinline__ void agg_body(
    const int* __restrict__ rowptr, const int* __restrict__ ssrc,
    const float* __restrict__ esrc, const float* __restrict__ edst,
    const unsigned short* __restrict__ hbuf, const float* __restrict__ b,
    float* __restrict__ out, int N) {
    constexpr int F = H * C;
    constexpr int AQ = (F + FPL - 1) / FPL;
    constexpr int S = L * G;
    constexpr int P = FPL / 2;           // f32x2 accumulators
    static_assert(S * NPW == 64, "wave layout");
    static_assert(AQ <= L, "lanes cover features");
    int lane = threadIdx.x & 63;
    int wave = threadIdx.x >> 6;
    int sub = lane / S;
    int ls = lane - sub * S;
    int g = ls / L, q = ls - g * L;
    int n = (blockIdx.x * 4 + wave) * NPW + sub;
    if (n >= N) return;
    const bool act = (q < AQ);
    int h = act ? (FPL * q) / C : 0;
    int qa = act ? q : 0;
    float edn = edst[n * H + h];
    int beg = rowptr[n], end = rowptr[n + 1];
    int kend = end - 1;                   // deg >= 1 (self loop) -> always valid
    float sum = 0.f;
    f32x2 acc[P];
#pragma unroll
    for (int i = 0; i < P; ++i) { acc[i].x = 0.f; acc[i].y = 0.f; }

    int k = beg + g;
    int ss[U];
#pragma unroll
    for (int u = 0; u < U; ++u) {
        int kk = k + u * G;
        ss[u] = ssrc[kk < kend ? kk : kend];
    }
    while (k < end) {
        uint4 hv4[U];
        uint2 hv2[U];
        float es[U];
#pragma unroll
        for (int u = 0; u < U; ++u) {
            if constexpr (FPL == 8) hv4[u] = ((const uint4*)hbuf)[ss[u] * RSL + qa];
            else hv2[u] = ((const uint2*)hbuf)[ss[u] * RSL + qa];
            es[u] = esrc[ss[u] * H + h];
        }
        int kn = k + U * G;
        int sn[U];
#pragma unroll
        for (int u = 0; u < U; ++u) {
            int kk = kn + u * G;
            sn[u] = ssrc[kk < kend ? kk : kend];
        }
        __builtin_amdgcn_sched_barrier(0);  // loads above must all issue first
#pragma unroll
        for (int u = 0; u < U; ++u) {
            float ex = (act && (k + u * G < end)) ? __expf(lrelu(es[u] + edn)) : 0.f;
            f32x2 exv; exv.x = ex; exv.y = ex;
            if constexpr (FPL == 8) {
                uint4 v = hv4[u];
                acc[0] = pkfma(exv, bfpair(v.x), acc[0]);
                acc[1] = pkfma(exv, bfpair(v.y), acc[1]);
                acc[2] = pkfma(exv, bfpair(v.z), acc[2]);
                acc[3] = pkfma(exv, bfpair(v.w), acc[3]);
            } else {
                uint2 v = hv2[u];
                acc[0] = pkfma(exv, bfpair(v.x), acc[0]);
                acc[1] = pkfma(exv, bfpair(v.y), acc[1]);
            }
            sum += ex;
        }
#pragma unroll
        for (int u = 0; u < U; ++u) ss[u] = sn[u];
        k = kn;
    }
#pragma unroll
    for (int step = L; step < S; step <<= 1) {
        sum += __shfl_xor(sum, step);
#pragma unroll
        for (int i = 0; i < P; ++i) {
            acc[i].x += __shfl_xor(acc[i].x, step);
            acc[i].y += __shfl_xor(acc[i].y, step);
        }
    }
    if (g == 0 && act) {
        float inv = 1.f / (sum + 1e-16f);
        float v[FPL];
#pragma unroll
        for (int i = 0; i < FPL; ++i) {
            float av = (i & 1) ? acc[i >> 1].y : acc[i >> 1].x;
            v[i] = av * inv + b[FPL * q + i];
            if (ELU) v[i] = v[i] > 0.f ? v[i] : __expf(v[i]) - 1.f;
        }
        float* op = out + n * F + FPL * q;
#pragma unroll
        for (int i = 0; i < FPL; i += 4)
            *(float4*)(op + i) = make_float4(v[i], v[i + 1], v[i + 2], v[i + 3]);
    }
}

// Distinct kernel names per layer for rocprof attribution (identical codegen).
__global__ __launch_bounds__(256) void agg1_kernel(
    const int* __restrict__ rowptr, const int* __restrict__ ssrc,
    const float* __restrict__ esrc, const float* __restrict__ edst,
    const unsigned short* __restrict__ hbuf, const float* __restrict__ b,
    float* __restrict__ out, int N) {
    agg_body<4, 4, 4, 8, 2, 4, 4, 5, true>(rowptr, ssrc, esrc, edst, hbuf, b, out, N);
}
__global__ __launch_bounds__(256) void agg2_kernel(
    const int* __restrict__ rowptr, const int* __restrict__ ssrc,
    const float* __restrict__ esrc, const float* __restrict__ edst,
    const unsigned short* __restrict__ hbuf, const float* __restrict__ b,
    float* __restrict__ out, int N) {
    agg_body<8, 8, 8, 8, 1, 8, 8, 5, true>(rowptr, ssrc, esrc, edst, hbuf, b, out, N);
}
__global__ __launch_bounds__(256) void agg3_kernel(
    const int* __restrict__ rowptr, const int* __restrict__ ssrc,
    const float* __restrict__ esrc, const float* __restrict__ edst,
    const unsigned short* __restrict__ hbuf, const float* __restrict__ b,
    float* __restrict__ out, int N) {
    agg_body<1, 40, 8, 8, 1, 8, 5, 5, false>(rowptr, ssrc, esrc, edst, hbuf, b, out, N);
}

static inline int cdiv(long a, int b) { return (int)((a + b - 1) / b); }

extern "C" void kernel_launch(void* const* d_in, const int* in_sizes, int n_in,
                              void* d_out, int out_size, void* d_ws, size_t ws_size,
                              hipStream_t stream) {
    const float* x1 = (const float*)d_in[0];
    const int* ei = (const int*)d_in[1];
    const int* src = ei;
    const int* dst = ei + NE;
    const float* W1 = (const float*)d_in[2];
    const float* as1 = (const float*)d_in[3];
    const float* ad1 = (const float*)d_in[4];
    const float* b1 = (const float*)d_in[5];
    const float* W2 = (const float*)d_in[6];
    const float* as2 = (const float*)d_in[7];
    const float* ad2 = (const float*)d_in[8];
    const float* b2 = (const float*)d_in[9];
    const float* W3 = (const float*)d_in[10];
    const float* as3 = (const float*)d_in[11];
    const float* ad3 = (const float*)d_in[12];
    const float* b3 = (const float*)d_in[13];
    float* out = (float*)d_out;

    // workspace carve (~80 MB)
    char* wsb = (char*)d_ws;
    unsigned short* hbuf = (unsigned short*)wsb;  wsb += (long)NN * 64 * 2;
    float* x2 = (float*)wsb;         wsb += (long)NN * 16 * 4;
    float* x3 = (float*)wsb;         wsb += (long)NN * 64 * 4;
    float* esrc = (float*)wsb;       wsb += (long)NN * 8 * 4;
    float* edst = (float*)wsb;       wsb += (long)NN * 8 * 4;
    unsigned* tmpp = (unsigned*)wsb; wsb += (long)ET * 4;
    int* ssrc = (int*)wsb;           wsb += (long)ET * 4;
    int* rowptr = (int*)wsb;         wsb += (long)(NN + 1) * 4;
    int* cnt = (int*)wsb;            wsb += (long)NBUC * NBLK * 4;
    int* bstart = (int*)wsb;         wsb += (long)(NBUC + 1) * 4;
    int* tot = (int*)wsb;            wsb += (long)NBUC * 4;

    const int B = 256;

    // ---- fused: CSR count (blocks 0..255) + layer-1 GEMM (rest) ----
    cntgemm_kernel<<<NBLK + cdiv((long)NN * 4, B), B, 0, stream>>>(
        dst, cnt, x1, W1, as1, ad1, hbuf, esrc, edst, NN);
    // ---- rest of CSR build ----
    rowsum_kernel<<<cdiv(NBUC, 4), B, 0, stream>>>(cnt, tot);
    scan_kernel<<<1, 1024, 0, stream>>>(tot, bstart);
    base_kernel<<<cdiv(NBUC, 4), B, 0, stream>>>(cnt, bstart);
    scatter_kernel<<<NBLK, 1024, 0, stream>>>(src, dst, cnt, tmpp);
    sort_kernel<<<NBUC, 1024, 0, stream>>>(bstart, tmpp, rowptr, ssrc);

    // ---- Layer 1 agg: H=4, C=4, ELU ----
    agg1_kernel<<<cdiv(NN, 8), B, 0, stream>>>(
        rowptr, ssrc, esrc, edst, hbuf, b1, x2, NN);

    // ---- Layer 2: 16 -> H=8, C=8 (concat 64), ELU ----
    gemm_attn_kernel<16, 64, 8><<<cdiv((long)NN * 16, B), B, 0, stream>>>(
        x2, W2, as2, ad2, hbuf, esrc, edst, NN);
    agg2_kernel<<<cdiv(NN, 4), B, 0, stream>>>(
        rowptr, ssrc, esrc, edst, hbuf, b2, x3, NN);

    // ---- Layer 3: 64 -> H=1, C=40, no concat, no ELU; rows packed at 80B,
    //      GEMM fused with attention logits ----
    gemm_attn3_kernel<<<cdiv(NN, 32), 320, 0, stream>>>(
        x3, W3, as3, ad3, hbuf, esrc, edst, NN);
    agg3_kernel<<<cdiv(NN, 4), B, 0, stream>>>(
        rowptr, ssrc, esrc, edst, hbuf, b3, out, NN);
}